// Round 5
// baseline (64.253 us; speedup 1.0000x reference)
//
#include <hip/hip_runtime.h>

#define HH 56
#define WWID 56
#define HWP (HH*WWID)      // 3136
#define BB 8
#define CC 64
#define NPIX (BB*HWP)      // 25088

// 8-lane-group all-reduce sum, DPP only (3 steps). All 8 lanes end with the sum.
__device__ __forceinline__ float grp_sum8(float x) {
  int xi;
  xi = __builtin_amdgcn_update_dpp(0, __float_as_int(x), 0xB1, 0xF, 0xF, true);  // quad_perm [1,0,3,2]  ^1
  x += __int_as_float(xi);
  xi = __builtin_amdgcn_update_dpp(0, __float_as_int(x), 0x4E, 0xF, 0xF, true);  // quad_perm [2,3,0,1]  ^2
  x += __int_as_float(xi);
  xi = __builtin_amdgcn_update_dpp(0, __float_as_int(x), 0x141, 0xF, 0xF, true); // row_half_mirror      ^4 (quads uniform)
  x += __int_as_float(xi);
  return x;
}

__device__ __forceinline__ float dot4(float4 a, float4 b) {
  float t = a.x * b.x;
  t = fmaf(a.y, b.y, t);
  t = fmaf(a.z, b.z, t);
  t = fmaf(a.w, b.w, t);
  return t;
}

// ---------------- qkv: 1x1 convs via 16KB LDS-staged x tile, 64 px/block ----------------
__global__ __launch_bounds__(512) void qkv_kernel(
    const float* __restrict__ x,
    const float* __restrict__ b1, const float* __restrict__ b2, const float* __restrict__ b3,
    const float* __restrict__ w1, const float* __restrict__ w2, const float* __restrict__ w3,
    float* __restrict__ q, float* __restrict__ k, float* __restrict__ v)
{
  __shared__ float xs[64 * 64];     // 16 KB: x[c][px]
  const int tid = threadIdx.x;

  // XCD-chunked swizzle: 392 blocks, 49 per image -> XCD n produces image n
  int bid = (int)blockIdx.x;
  bid = (bid & 7) * 49 + (bid >> 3);

  const int pix0 = bid * 64;
  const int n    = pix0 / HWP;
  const int hw0  = pix0 - n * HWP;
  const float* xb = x + (size_t)n * CC * HWP + hw0;

  // stage x tile: 4096 floats = 1024 float4, 2 per thread, fully coalesced
  #pragma unroll
  for (int r = 0; r < 2; ++r) {
    int idx = r * 512 + tid;        // 0..1023
    int c   = idx >> 4;
    int p4  = (idx & 15) * 4;
    *reinterpret_cast<float4*>(&xs[c*64 + p4]) =
        *reinterpret_cast<const float4*>(xb + (size_t)c * HWP + p4);
  }
  __syncthreads();

  const int o = tid & 63;
  const int g = __builtin_amdgcn_readfirstlane((int)(tid >> 6));   // wave 0..7, 8 px each

  float accq[8], acck[8], accv[8];
  const float bq = b1[o], bk = b2[o], bv = b3[o];
  #pragma unroll
  for (int p = 0; p < 8; ++p) { accq[p] = bq; acck[p] = bk; accv[p] = bv; }

  #pragma unroll 4
  for (int c4 = 0; c4 < 16; ++c4) {
    const float4 wq  = *reinterpret_cast<const float4*>(w1 + o*64 + c4*4);
    const float4 wk  = *reinterpret_cast<const float4*>(w2 + o*64 + c4*4);
    const float4 wv4 = *reinterpret_cast<const float4*>(w3 + o*64 + c4*4);
    const float wqa[4] = {wq.x, wq.y, wq.z, wq.w};
    const float wka[4] = {wk.x, wk.y, wk.z, wk.w};
    const float wva[4] = {wv4.x, wv4.y, wv4.z, wv4.w};
    #pragma unroll
    for (int e = 0; e < 4; ++e) {
      const float* xr = &xs[(c4*4 + e)*64 + g*8];
      float4 x0 = *reinterpret_cast<const float4*>(xr);        // uniform -> broadcast
      float4 x1 = *reinterpret_cast<const float4*>(xr + 4);
      float xf[8] = {x0.x, x0.y, x0.z, x0.w, x1.x, x1.y, x1.z, x1.w};
      #pragma unroll
      for (int p = 0; p < 8; ++p) {
        accq[p] = fmaf(wqa[e], xf[p], accq[p]);
        acck[p] = fmaf(wka[e], xf[p], acck[p]);
        accv[p] = fmaf(wva[e], xf[p], accv[p]);
      }
    }
  }

  const int pbase = pix0 + g * 8;
  #pragma unroll
  for (int p = 0; p < 8; ++p) {
    size_t off = (size_t)(pbase + p) * 64 + o;   // lanes o consecutive -> 256B stores
    q[off] = accq[p]; k[off] = acck[p]; v[off] = accv[p];
  }
}

// ---------------- fused attention (5x5 reflect) + folded depthwise conv (3x3 zero-pad) ----------------
// block = 256 threads = 32 pixels; 8-lane group per pixel, lane holds 8 channels.
// Conv k/v loads are reused from the attention window (in-bounds tap address == reflected address).
__global__ __launch_bounds__(256) void attn_kernel(
    const float* __restrict__ q, const float* __restrict__ k, const float* __restrict__ v,
    const float* __restrict__ wp,
    const float* __restrict__ w_fc, const float* __restrict__ w_dep,
    const float* __restrict__ b_dep, const float* __restrict__ rate1, const float* __restrict__ rate2,
    float* __restrict__ out)
{
  __shared__ float stab[27 * 64];
  __shared__ float sout[32 * 68];

  const int tid = threadIdx.x;
  // fold conv taps in-block: tab[(br*9+tap)*64+d] = sum_o w_dep[d,o,tap]*w_fc[o,br]
  for (int idx = tid; idx < 27*64; idx += 256) {
    int d = idx & 63, bt = idx >> 6;
    int br = bt / 9, tap = bt - br*9;
    float s = 0.f;
    #pragma unroll
    for (int oo = 0; oo < 9; ++oo)
      s += w_dep[d*81 + oo*9 + tap] * w_fc[oo*3 + br];
    stab[idx] = s;
  }
  __syncthreads();

  const int lane = tid & 63;
  const int wid  = __builtin_amdgcn_readfirstlane((int)(tid >> 6));
  const int grp  = lane >> 3;          // pixel group within wave (0..7)
  const int sl   = lane & 7;           // sub-lane = d/8

  // XCD-chunked swizzle: 784 blocks, 98 per image -> XCD n consumes image n
  int bid = (int)blockIdx.x;
  bid = (bid & 7) * 98 + (bid >> 3);

  const int pixbase = bid * 32;        // blocks never cross images (3136 % 32 == 0)
  const int pl  = wid * 8 + grp;       // local pixel 0..31
  const int pix = pixbase + pl;
  const int n   = pix / HWP;
  const int hw  = pix - n * HWP;
  const int h   = hw / WWID;
  const int w   = hw - h * WWID;

  const size_t nbase = (size_t)n * HWP * 64;
  const float* qp = q + nbase + (size_t)hw * 64 + sl * 8;
  const float4 q4a = *reinterpret_cast<const float4*>(qp);
  const float4 q4b = *reinterpret_cast<const float4*>(qp + 4);

  // RPE dots; wp layout [d][2]
  const float4 wA = *reinterpret_cast<const float4*>(wp + sl*16);
  const float4 wB = *reinterpret_cast<const float4*>(wp + sl*16 + 4);
  const float4 wC = *reinterpret_cast<const float4*>(wp + sl*16 + 8);
  const float4 wD = *reinterpret_cast<const float4*>(wp + sl*16 + 12);
  const float4 wpx0 = {wA.x, wA.z, wB.x, wB.z};
  const float4 wpx1 = {wC.x, wC.z, wD.x, wD.z};
  const float4 wpy0 = {wA.y, wA.w, wB.y, wB.w};
  const float4 wpy1 = {wC.y, wC.w, wD.y, wD.w};
  const float qw0 = grp_sum8(dot4(q4a, wpx0) + dot4(q4b, wpx1));
  const float qw1 = grp_sum8(dot4(q4a, wpy0) + dot4(q4b, wpy1));

  // reflected coordinates for the 5x5 window
  int hr[5], wr[5];
  #pragma unroll
  for (int i = 0; i < 5; ++i) {
    int t = h + i - 2; hr[i] = t < 0 ? -t : (t >= HH ? 2*HH - 2 - t : t);
    t = w + i - 2;     wr[i] = t < 0 ? -t : (t >= WWID ? 2*WWID - 2 - t : t);
  }

  const float C = 2.0f / 55.0f;
  const float A0 = 0.125f * qw0 * C;   // coeff for (w - wr)
  const float A1 = 0.125f * qw1 * C;   // coeff for (h - hr)

  // pass 1: QK^T rows + conv-k contribution (reuses kk loads)
  const float* kb = k + nbase + sl * 8;
  float att[25];
  float4 c0 = {0.f,0.f,0.f,0.f}, c1 = {0.f,0.f,0.f,0.f};   // conv accumulator (k,v,q parts)
  #pragma unroll
  for (int i = 0; i < 5; ++i) {
    const float* krow = kb + (size_t)(hr[i] * WWID) * 64;
    float4 ka[5], kb4[5];
    #pragma unroll
    for (int j = 0; j < 5; ++j) {
      ka[j]  = *reinterpret_cast<const float4*>(krow + wr[j] * 64);
      kb4[j] = *reinterpret_cast<const float4*>(krow + wr[j] * 64 + 4);
    }
    const float rh = A1 * (float)(h - hr[i]);
    #pragma unroll
    for (int j = 0; j < 5; ++j) {
      const float d8 = grp_sum8(dot4(q4a, ka[j]) + dot4(q4b, kb4[j]));
      att[i*5 + j] = 0.125f * d8 + A0 * (float)(w - wr[j]) + rh;
    }
    if (i >= 1 && i <= 3) {
      const int hh = h + i - 2;
      #pragma unroll
      for (int kw = 0; kw < 3; ++kw) {
        const int wc = w + kw - 1;
        const float mk = (((unsigned)hh < HH) && ((unsigned)wc < WWID)) ? 1.f : 0.f;
        const int tap = (i-1)*3 + kw;
        const float4 t0 = *reinterpret_cast<const float4*>(&stab[(9 + tap)*64 + sl*8]);
        const float4 t1 = *reinterpret_cast<const float4*>(&stab[(9 + tap)*64 + sl*8 + 4]);
        const int j = kw + 1;
        c0.x = fmaf(mk * t0.x, ka[j].x, c0.x);
        c0.y = fmaf(mk * t0.y, ka[j].y, c0.y);
        c0.z = fmaf(mk * t0.z, ka[j].z, c0.z);
        c0.w = fmaf(mk * t0.w, ka[j].w, c0.w);
        c1.x = fmaf(mk * t1.x, kb4[j].x, c1.x);
        c1.y = fmaf(mk * t1.y, kb4[j].y, c1.y);
        c1.z = fmaf(mk * t1.z, kb4[j].z, c1.z);
        c1.w = fmaf(mk * t1.w, kb4[j].w, c1.w);
      }
    }
  }

  // softmax over 25 (redundant across the 8 lanes of the group)
  float m = att[0];
  #pragma unroll
  for (int p = 1; p < 25; ++p) m = fmaxf(m, att[p]);
  float s = 0.f;
  #pragma unroll
  for (int p = 0; p < 25; ++p) { att[p] = __expf(att[p] - m); s += att[p]; }
  const float inv = 1.0f / s;

  // pass 2: PV + conv-v (reuses vv loads) + conv-q (9 extra loads)
  const float* vb = v + nbase + sl * 8;
  float4 o0 = {0.f,0.f,0.f,0.f}, o1 = {0.f,0.f,0.f,0.f};
  #pragma unroll
  for (int i = 0; i < 5; ++i) {
    const float* vrow = vb + (size_t)(hr[i] * WWID) * 64;
    float4 va[5], vb4[5];
    #pragma unroll
    for (int j = 0; j < 5; ++j) {
      va[j]  = *reinterpret_cast<const float4*>(vrow + wr[j] * 64);
      vb4[j] = *reinterpret_cast<const float4*>(vrow + wr[j] * 64 + 4);
    }
    #pragma unroll
    for (int j = 0; j < 5; ++j) {
      const float a = att[i*5 + j];
      o0.x = fmaf(a, va[j].x, o0.x);
      o0.y = fmaf(a, va[j].y, o0.y);
      o0.z = fmaf(a, va[j].z, o0.z);
      o0.w = fmaf(a, va[j].w, o0.w);
      o1.x = fmaf(a, vb4[j].x, o1.x);
      o1.y = fmaf(a, vb4[j].y, o1.y);
      o1.z = fmaf(a, vb4[j].z, o1.z);
      o1.w = fmaf(a, vb4[j].w, o1.w);
    }
    if (i >= 1 && i <= 3) {
      const int hh = h + i - 2;
      #pragma unroll
      for (int kw = 0; kw < 3; ++kw) {
        const int wc = w + kw - 1;
        const float mk = (((unsigned)hh < HH) && ((unsigned)wc < WWID)) ? 1.f : 0.f;
        const int tap = (i-1)*3 + kw;
        const int j = kw + 1;
        // conv-v
        const float4 t0 = *reinterpret_cast<const float4*>(&stab[(18 + tap)*64 + sl*8]);
        const float4 t1 = *reinterpret_cast<const float4*>(&stab[(18 + tap)*64 + sl*8 + 4]);
        c0.x = fmaf(mk * t0.x, va[j].x, c0.x);
        c0.y = fmaf(mk * t0.y, va[j].y, c0.y);
        c0.z = fmaf(mk * t0.z, va[j].z, c0.z);
        c0.w = fmaf(mk * t0.w, va[j].w, c0.w);
        c1.x = fmaf(mk * t1.x, vb4[j].x, c1.x);
        c1.y = fmaf(mk * t1.y, vb4[j].y, c1.y);
        c1.z = fmaf(mk * t1.z, vb4[j].z, c1.z);
        c1.w = fmaf(mk * t1.w, vb4[j].w, c1.w);
        // conv-q (extra loads at the same reflected address)
        const float* qrow = q + nbase + (size_t)(hr[i]*WWID + wr[j]) * 64 + sl * 8;
        const float4 qa = *reinterpret_cast<const float4*>(qrow);
        const float4 qb2 = *reinterpret_cast<const float4*>(qrow + 4);
        const float4 u0 = *reinterpret_cast<const float4*>(&stab[(0 + tap)*64 + sl*8]);
        const float4 u1 = *reinterpret_cast<const float4*>(&stab[(0 + tap)*64 + sl*8 + 4]);
        c0.x = fmaf(mk * u0.x, qa.x, c0.x);
        c0.y = fmaf(mk * u0.y, qa.y, c0.y);
        c0.z = fmaf(mk * u0.z, qa.z, c0.z);
        c0.w = fmaf(mk * u0.w, qa.w, c0.w);
        c1.x = fmaf(mk * u1.x, qb2.x, c1.x);
        c1.y = fmaf(mk * u1.y, qb2.y, c1.y);
        c1.z = fmaf(mk * u1.z, qb2.z, c1.z);
        c1.w = fmaf(mk * u1.w, qb2.w, c1.w);
      }
    }
  }

  const float4 bd0 = *reinterpret_cast<const float4*>(b_dep + sl*8);
  const float4 bd1 = *reinterpret_cast<const float4*>(b_dep + sl*8 + 4);
  const float r1 = rate1[0] * inv;
  const float r2 = rate2[0];

  float4 s0, s1;
  s0.x = r1 * o0.x + r2 * (c0.x + bd0.x);
  s0.y = r1 * o0.y + r2 * (c0.y + bd0.y);
  s0.z = r1 * o0.z + r2 * (c0.z + bd0.z);
  s0.w = r1 * o0.w + r2 * (c0.w + bd0.w);
  s1.x = r1 * o1.x + r2 * (c1.x + bd1.x);
  s1.y = r1 * o1.y + r2 * (c1.y + bd1.y);
  s1.z = r1 * o1.z + r2 * (c1.z + bd1.z);
  s1.w = r1 * o1.w + r2 * (c1.w + bd1.w);

  // stage to LDS [px][68] then write coalesced float4 pairs per thread
  *reinterpret_cast<float4*>(&sout[pl*68 + sl*8])     = s0;
  *reinterpret_cast<float4*>(&sout[pl*68 + sl*8 + 4]) = s1;
  __syncthreads();

  const int c   = tid >> 2;          // channel 0..63
  const int seg = tid & 3;           // px segment of 8
  const int n0  = pixbase / HWP;
  const int hwb = pixbase - n0 * HWP + seg * 8;
  float r[8];
  #pragma unroll
  for (int t2 = 0; t2 < 8; ++t2) r[t2] = sout[(seg*8 + t2)*68 + c];
  float* ob = out + ((size_t)(n0*64 + c))*HWP + hwb;
  float4 u0 = {r[0], r[1], r[2], r[3]};
  float4 u1 = {r[4], r[5], r[6], r[7]};
  *reinterpret_cast<float4*>(ob)     = u0;
  *reinterpret_cast<float4*>(ob + 4) = u1;
}

extern "C" void kernel_launch(void* const* d_in, const int* in_sizes, int n_in,
                              void* d_out, int out_size, void* d_ws, size_t ws_size,
                              hipStream_t stream) {
  const float* x     = (const float*)d_in[0];
  const float* w1    = (const float*)d_in[1];
  const float* b1    = (const float*)d_in[2];
  const float* w2    = (const float*)d_in[3];
  const float* b2    = (const float*)d_in[4];
  const float* w3    = (const float*)d_in[5];
  const float* b3    = (const float*)d_in[6];
  const float* wp    = (const float*)d_in[7];
  // d_in[8] = bp : cancels in the RPE difference, unused
  const float* w_fc  = (const float*)d_in[9];
  const float* w_dep = (const float*)d_in[10];
  const float* b_dep = (const float*)d_in[11];
  const float* rate1 = (const float*)d_in[12];
  const float* rate2 = (const float*)d_in[13];
  float* out = (float*)d_out;

  float* ws = (float*)d_ws;
  float* q = ws;                       // NPIX*64
  float* k = ws + (size_t)NPIX*64;
  float* v = ws + (size_t)2*NPIX*64;

  qkv_kernel<<<NPIX/64, 512, 0, stream>>>(x, b1, b2, b3, w1, w2, w3, q, k, v);
  attn_kernel<<<NPIX/32, 256, 0, stream>>>(q, k, v, wp, w_fc, w_dep, b_dep, rate1, rate2, out);
}

// Round 6
// 45.100 us; speedup vs baseline: 1.4247x; 1.4247x over previous
//
#include <hip/hip_runtime.h>

#define HH 56
#define WWID 56
#define HWP (HH*WWID)      // 3136
#define BB 8
#define CC 64
#define NPIX (BB*HWP)      // 25088

// 16-lane-group all-reduce sum, DPP only. All 16 lanes end with the sum.
__device__ __forceinline__ float grp_sum(float x) {
  int xi;
  xi = __builtin_amdgcn_update_dpp(0, __float_as_int(x), 0xB1, 0xF, 0xF, true);  // quad_perm [1,0,3,2]
  x += __int_as_float(xi);
  xi = __builtin_amdgcn_update_dpp(0, __float_as_int(x), 0x4E, 0xF, 0xF, true);  // quad_perm [2,3,0,1]
  x += __int_as_float(xi);
  xi = __builtin_amdgcn_update_dpp(0, __float_as_int(x), 0x141, 0xF, 0xF, true); // row_half_mirror
  x += __int_as_float(xi);
  xi = __builtin_amdgcn_update_dpp(0, __float_as_int(x), 0x140, 0xF, 0xF, true); // row_mirror
  x += __int_as_float(xi);
  return x;
}

__device__ __forceinline__ float dot4(float4 a, float4 b) {
  float t = a.x * b.x;
  t = fmaf(a.y, b.y, t);
  t = fmaf(a.z, b.z, t);
  t = fmaf(a.w, b.w, t);
  return t;
}

// ---------------- prep: pack w1/w2/w3 to [c/4][o][4], fold conv taps ----------------
__global__ __launch_bounds__(256) void prep_kernel(
    const float* __restrict__ w1, const float* __restrict__ w2, const float* __restrict__ w3,
    const float* __restrict__ w_fc, const float* __restrict__ w_dep,
    float* __restrict__ w1P, float* __restrict__ w2P, float* __restrict__ w3P,
    float* __restrict__ tab)
{
  const int t = threadIdx.x;
  for (int idx = t; idx < 64*64; idx += 256) {
    int c4 = idx >> 8, r = idx & 255, o = r >> 2, e = r & 3;
    int c = c4*4 + e;
    w1P[idx] = w1[o*64 + c];
    w2P[idx] = w2[o*64 + c];
    w3P[idx] = w3[o*64 + c];
  }
  // tab[(br*9+tap)*64 + d] = sum_o w_dep[d,o,tap] * w_fc[o,br]
  for (int idx = t; idx < 27*64; idx += 256) {
    int d = idx & 63, bt = idx >> 6;
    int br = bt / 9, tap = bt - br*9;
    float s = 0.f;
    #pragma unroll
    for (int oo = 0; oo < 9; ++oo)
      s += w_dep[d*81 + oo*9 + tap] * w_fc[oo*3 + br];
    tab[idx] = s;
  }
}

// ---------------- qkv: 1x1 convs via LDS-staged x tile (round-4 proven) ----------------
// block = 256 threads = 32 pixels; lane = output channel o, wave g owns 8 pixels.
__global__ __launch_bounds__(256) void qkv_kernel(
    const float* __restrict__ x,
    const float* __restrict__ b1, const float* __restrict__ b2, const float* __restrict__ b3,
    const float* __restrict__ w1P, const float* __restrict__ w2P, const float* __restrict__ w3P,
    float* __restrict__ q, float* __restrict__ k, float* __restrict__ v)
{
  __shared__ float xs[64 * 32];     // 8 KB: x[c][px]
  const int tid = threadIdx.x;

  // XCD-chunked swizzle: 784 blocks, 98 per image -> XCD n produces image n
  int bid = (int)blockIdx.x;
  bid = (bid & 7) * 98 + (bid >> 3);

  const int pix0 = bid * 32;
  const int n    = pix0 / HWP;
  const int hw0  = pix0 - n * HWP;
  const float* xb = x + (size_t)n * CC * HWP + hw0;

  // stage x tile: 2048 floats, 2 x float4 per thread, fully coalesced
  #pragma unroll
  for (int r = 0; r < 2; ++r) {
    int idx = r * 256 + tid;        // 0..511
    int c   = idx >> 3;
    int p4  = (idx & 7) * 4;
    float4 xv = *reinterpret_cast<const float4*>(xb + (size_t)c * HWP + p4);
    *reinterpret_cast<float4*>(&xs[c*32 + p4]) = xv;
  }
  __syncthreads();

  const int o = tid & 63;
  const int g = __builtin_amdgcn_readfirstlane((int)(tid >> 6));   // pixel group 0..3

  float accq[8], acck[8], accv[8];
  const float bq = b1[o], bk = b2[o], bv = b3[o];
  #pragma unroll
  for (int p = 0; p < 8; ++p) { accq[p] = bq; acck[p] = bk; accv[p] = bv; }

  #pragma unroll 2
  for (int c4 = 0; c4 < 16; ++c4) {
    const float4 wq  = *reinterpret_cast<const float4*>(w1P + c4*256 + o*4);
    const float4 wk  = *reinterpret_cast<const float4*>(w2P + c4*256 + o*4);
    const float4 wv4 = *reinterpret_cast<const float4*>(w3P + c4*256 + o*4);
    const float wqa[4] = {wq.x, wq.y, wq.z, wq.w};
    const float wka[4] = {wk.x, wk.y, wk.z, wk.w};
    const float wva[4] = {wv4.x, wv4.y, wv4.z, wv4.w};
    #pragma unroll
    for (int e = 0; e < 4; ++e) {
      const float* xr = &xs[(c4*4 + e)*32 + g*8];
      float4 x0 = *reinterpret_cast<const float4*>(xr);        // uniform -> broadcast
      float4 x1 = *reinterpret_cast<const float4*>(xr + 4);
      float xf[8] = {x0.x, x0.y, x0.z, x0.w, x1.x, x1.y, x1.z, x1.w};
      #pragma unroll
      for (int p = 0; p < 8; ++p) {
        accq[p] = fmaf(wqa[e], xf[p], accq[p]);
        acck[p] = fmaf(wka[e], xf[p], acck[p]);
        accv[p] = fmaf(wva[e], xf[p], accv[p]);
      }
    }
  }

  const int pbase = pix0 + g * 8;
  #pragma unroll
  for (int p = 0; p < 8; ++p) {
    size_t off = (size_t)(pbase + p) * 64 + o;   // lanes o consecutive -> 256B stores
    q[off] = accq[p]; k[off] = acck[p]; v[off] = accv[p];
  }
}

// ---------------- fused attention + conv, single pass, online softmax ----------------
// block = 256 threads = 16 pixels; 16-lane group per pixel, lane holds 4 channels.
// Per window row: K and V loaded together (10 loads in flight); conv k/v taps reuse
// the window registers (in-bounds tap addr == reflected addr, OOB masked); 9 extra q loads.
__global__ __launch_bounds__(256) void attn_kernel(
    const float* __restrict__ q, const float* __restrict__ k, const float* __restrict__ v,
    const float* __restrict__ wp, const float* __restrict__ tab,
    const float* __restrict__ b_dep, const float* __restrict__ rate1, const float* __restrict__ rate2,
    float* __restrict__ out)
{
  __shared__ float stab[27 * 64];
  __shared__ float sbd[64];
  __shared__ float sout[64 * 17];

  const int tid  = threadIdx.x;
  for (int i = tid; i < 27*64; i += 256) stab[i] = tab[i];
  if (tid < 64) sbd[tid] = b_dep[tid];
  __syncthreads();

  const int lane = tid & 63;
  const int wid  = __builtin_amdgcn_readfirstlane((int)(tid >> 6));
  const int grp  = lane >> 4;          // group within wave (0..3)
  const int sl   = lane & 15;          // sub-lane = d/4

  // XCD-chunked swizzle: 1568 blocks, 196 per image -> XCD n consumes image n
  int bid = (int)blockIdx.x;
  bid = (bid & 7) * 196 + (bid >> 3);

  const int pixbase = bid * 16;
  const int pl  = wid * 4 + grp;       // local pixel 0..15
  const int pix = pixbase + pl;
  const int n   = pix / HWP;           // uniform per block
  const int hw  = pix - n * HWP;
  const int h   = hw / WWID;
  const int w   = hw - h * WWID;

  const size_t nbase = (size_t)n * HWP * 64;
  const float4 q4 = *reinterpret_cast<const float4*>(q + nbase + (size_t)hw * 64 + sl * 4);

  // RPE dots; wp layout [d][2]
  const float4 wa = *reinterpret_cast<const float4*>(wp + 8 * sl);
  const float4 wb = *reinterpret_cast<const float4*>(wp + 8 * sl + 4);
  const float4 wpx4 = {wa.x, wa.z, wb.x, wb.z};
  const float4 wpy4 = {wa.y, wa.w, wb.y, wb.w};
  const float qw0 = grp_sum(dot4(q4, wpx4));
  const float qw1 = grp_sum(dot4(q4, wpy4));

  // reflected coordinates for the 5x5 window
  int hr[5], wr[5];
  #pragma unroll
  for (int i = 0; i < 5; ++i) {
    int t = h + i - 2; hr[i] = t < 0 ? -t : (t >= HH ? 2*HH - 2 - t : t);
    t = w + i - 2;     wr[i] = t < 0 ? -t : (t >= WWID ? 2*WWID - 2 - t : t);
  }

  const float C = 2.0f / 55.0f;
  const float A0 = 0.125f * qw0 * C;   // coeff for (w - wr)
  const float A1 = 0.125f * qw1 * C;   // coeff for (h - hr)

  const float* kb = k + nbase + sl * 4;
  const float* vb = v + nbase + sl * 4;

  float m = -__builtin_inff();
  float s = 0.f;
  float4 oatt = {0.f, 0.f, 0.f, 0.f};
  float4 cacc = {0.f, 0.f, 0.f, 0.f};

  #pragma unroll
  for (int i = 0; i < 5; ++i) {
    const size_t rowoff = (size_t)(hr[i] * WWID) * 64;
    const float* krow = kb + rowoff;
    const float* vrow = vb + rowoff;
    float4 ka[5], va[5];
    #pragma unroll
    for (int j = 0; j < 5; ++j) ka[j] = *reinterpret_cast<const float4*>(krow + wr[j] * 64);
    #pragma unroll
    for (int j = 0; j < 5; ++j) va[j] = *reinterpret_cast<const float4*>(vrow + wr[j] * 64);

    const float rh = A1 * (float)(h - hr[i]);
    float att[5];
    #pragma unroll
    for (int j = 0; j < 5; ++j) {
      const float d8 = grp_sum(dot4(q4, ka[j]));
      att[j] = 0.125f * d8 + A0 * (float)(w - wr[j]) + rh;
    }

    // online softmax update
    float mrow = att[0];
    #pragma unroll
    for (int j = 1; j < 5; ++j) mrow = fmaxf(mrow, att[j]);
    const float mnew = fmaxf(m, mrow);
    const float scale = __expf(m - mnew);
    m = mnew;
    s *= scale;
    oatt.x *= scale; oatt.y *= scale; oatt.z *= scale; oatt.w *= scale;
    #pragma unroll
    for (int j = 0; j < 5; ++j) {
      const float p = __expf(att[j] - m);
      s += p;
      oatt.x = fmaf(p, va[j].x, oatt.x);
      oatt.y = fmaf(p, va[j].y, oatt.y);
      oatt.z = fmaf(p, va[j].z, oatt.z);
      oatt.w = fmaf(p, va[j].w, oatt.w);
    }

    // conv branch: taps live in window rows 1..3, cols 1..3 (reuse ka/va regs)
    if (i >= 1 && i <= 3) {
      const int hh = h + i - 2;
      #pragma unroll
      for (int kw = 0; kw < 3; ++kw) {
        const int wc = w + kw - 1;
        const float mk = (((unsigned)hh < HH) && ((unsigned)wc < WWID)) ? 1.f : 0.f;
        const int tap = (i-1)*3 + kw;
        const int j = kw + 1;
        const float4 tq = *reinterpret_cast<const float4*>(&stab[(0*9 + tap)*64 + sl*4]);
        const float4 tk = *reinterpret_cast<const float4*>(&stab[(1*9 + tap)*64 + sl*4]);
        const float4 tv = *reinterpret_cast<const float4*>(&stab[(2*9 + tap)*64 + sl*4]);
        const float4 qn = *reinterpret_cast<const float4*>(q + nbase + (size_t)(hr[i]*WWID + wr[j]) * 64 + sl * 4);
        float sx = tq.x*qn.x; sx = fmaf(tk.x, ka[j].x, sx); sx = fmaf(tv.x, va[j].x, sx);
        float sy = tq.y*qn.y; sy = fmaf(tk.y, ka[j].y, sy); sy = fmaf(tv.y, va[j].y, sy);
        float sz = tq.z*qn.z; sz = fmaf(tk.z, ka[j].z, sz); sz = fmaf(tv.z, va[j].z, sz);
        float sw = tq.w*qn.w; sw = fmaf(tk.w, ka[j].w, sw); sw = fmaf(tv.w, va[j].w, sw);
        cacc.x = fmaf(mk, sx, cacc.x);
        cacc.y = fmaf(mk, sy, cacc.y);
        cacc.z = fmaf(mk, sz, cacc.z);
        cacc.w = fmaf(mk, sw, cacc.w);
      }
    }
  }

  const float inv = 1.0f / s;
  const float bdx = sbd[sl*4+0], bdy = sbd[sl*4+1], bdz = sbd[sl*4+2], bdw = sbd[sl*4+3];
  const float r1 = rate1[0] * inv;
  const float r2 = rate2[0];

  float res[4];
  res[0] = r1 * oatt.x + r2 * (cacc.x + bdx);
  res[1] = r1 * oatt.y + r2 * (cacc.y + bdy);
  res[2] = r1 * oatt.z + r2 * (cacc.z + bdz);
  res[3] = r1 * oatt.w + r2 * (cacc.w + bdw);

  // stage to LDS [ch][16 px + pad] then write coalesced float4 per thread
  #pragma unroll
  for (int e = 0; e < 4; ++e)
    sout[(4*sl + e)*17 + pl] = res[e];
  __syncthreads();

  const int c  = tid >> 2;
  const int e4 = (tid & 3) * 4;
  const int hw0 = pixbase - n * HWP;
  float4 o4 = {sout[c*17 + e4 + 0], sout[c*17 + e4 + 1],
               sout[c*17 + e4 + 2], sout[c*17 + e4 + 3]};
  *reinterpret_cast<float4*>(out + ((size_t)(n*64 + c))*HWP + hw0 + e4) = o4;
}

extern "C" void kernel_launch(void* const* d_in, const int* in_sizes, int n_in,
                              void* d_out, int out_size, void* d_ws, size_t ws_size,
                              hipStream_t stream) {
  const float* x     = (const float*)d_in[0];
  const float* w1    = (const float*)d_in[1];
  const float* b1    = (const float*)d_in[2];
  const float* w2    = (const float*)d_in[3];
  const float* b2    = (const float*)d_in[4];
  const float* w3    = (const float*)d_in[5];
  const float* b3    = (const float*)d_in[6];
  const float* wp    = (const float*)d_in[7];
  // d_in[8] = bp : cancels in the RPE difference, unused
  const float* w_fc  = (const float*)d_in[9];
  const float* w_dep = (const float*)d_in[10];
  const float* b_dep = (const float*)d_in[11];
  const float* rate1 = (const float*)d_in[12];
  const float* rate2 = (const float*)d_in[13];
  float* out = (float*)d_out;

  float* ws = (float*)d_ws;
  float* q   = ws;                       // NPIX*64
  float* k   = ws + (size_t)NPIX*64;
  float* v   = ws + (size_t)2*NPIX*64;
  float* w1P = ws + (size_t)3*NPIX*64;   // 4096
  float* w2P = w1P + 4096;
  float* w3P = w2P + 4096;
  float* tab = w3P + 4096;               // 27*64

  prep_kernel<<<1, 256, 0, stream>>>(w1, w2, w3, w_fc, w_dep, w1P, w2P, w3P, tab);
  qkv_kernel<<<NPIX/32, 256, 0, stream>>>(x, b1, b2, b3, w1P, w2P, w3P, q, k, v);
  attn_kernel<<<NPIX/16, 256, 0, stream>>>(q, k, v, wp, tab, b_dep, rate1, rate2, out);
}

// Round 7
// 40.249 us; speedup vs baseline: 1.5964x; 1.1205x over previous
//
#include <hip/hip_runtime.h>

#define HH 56
#define WWID 56
#define HWP (HH*WWID)      // 3136
#define BB 8
#define CC 64
#define NPIX (BB*HWP)      // 25088

// 16-lane-group all-reduce sum, DPP only. All 16 lanes end with the sum.
__device__ __forceinline__ float grp_sum(float x) {
  int xi;
  xi = __builtin_amdgcn_update_dpp(0, __float_as_int(x), 0xB1, 0xF, 0xF, true);  // quad_perm [1,0,3,2]
  x += __int_as_float(xi);
  xi = __builtin_amdgcn_update_dpp(0, __float_as_int(x), 0x4E, 0xF, 0xF, true);  // quad_perm [2,3,0,1]
  x += __int_as_float(xi);
  xi = __builtin_amdgcn_update_dpp(0, __float_as_int(x), 0x141, 0xF, 0xF, true); // row_half_mirror
  x += __int_as_float(xi);
  xi = __builtin_amdgcn_update_dpp(0, __float_as_int(x), 0x140, 0xF, 0xF, true); // row_mirror
  x += __int_as_float(xi);
  return x;
}

__device__ __forceinline__ float dot4(float4 a, float4 b) {
  float t = a.x * b.x;
  t = fmaf(a.y, b.y, t);
  t = fmaf(a.z, b.z, t);
  t = fmaf(a.w, b.w, t);
  return t;
}

// static-index component extract (folds at compile time under full unroll)
__device__ __forceinline__ float fcomp(const float4 v, int i) {
  return i == 0 ? v.x : i == 1 ? v.y : i == 2 ? v.z : v.w;
}

// ---------------- prep: pack w1/w2/w3 to [c/4][o][4], fold conv taps (16 blocks) ----------------
__global__ __launch_bounds__(256) void prep_kernel(
    const float* __restrict__ w1, const float* __restrict__ w2, const float* __restrict__ w3,
    const float* __restrict__ w_fc, const float* __restrict__ w_dep,
    float* __restrict__ w1P, float* __restrict__ w2P, float* __restrict__ w3P,
    float* __restrict__ tab)
{
  const int gt = blockIdx.x * 256 + threadIdx.x;   // 0..4095
  {
    const int idx = gt;
    const int c4 = idx >> 8, r = idx & 255, o = r >> 2, e = r & 3;
    const int c = c4*4 + e;
    w1P[idx] = w1[o*64 + c];
    w2P[idx] = w2[o*64 + c];
    w3P[idx] = w3[o*64 + c];
  }
  if (gt < 27*64) {
    const int d = gt & 63, bt = gt >> 6;
    const int br = bt / 9, tap = bt - br*9;
    float s = 0.f;
    #pragma unroll
    for (int oo = 0; oo < 9; ++oo)
      s += w_dep[d*81 + oo*9 + tap] * w_fc[oo*3 + br];
    tab[gt] = s;
  }
}

// ---------------- qkv: 1x1 convs via LDS-staged x tile, software-pipelined ----------------
// block = 256 threads = 32 pixels; lane = output channel o, wave g owns 8 pixels.
// x-tile reads double-buffered at 2-channel granularity; weights prefetched one c4 ahead.
__global__ __launch_bounds__(256) void qkv_kernel(
    const float* __restrict__ x,
    const float* __restrict__ b1, const float* __restrict__ b2, const float* __restrict__ b3,
    const float* __restrict__ w1P, const float* __restrict__ w2P, const float* __restrict__ w3P,
    float* __restrict__ q, float* __restrict__ k, float* __restrict__ v)
{
  __shared__ float xs[64 * 32];     // 8 KB: x[c][px]
  const int tid = threadIdx.x;

  // XCD-chunked swizzle: 784 blocks, 98 per image -> XCD n produces image n
  int bid = (int)blockIdx.x;
  bid = (bid & 7) * 98 + (bid >> 3);

  const int pix0 = bid * 32;
  const int n    = pix0 / HWP;
  const int hw0  = pix0 - n * HWP;
  const float* xb = x + (size_t)n * CC * HWP + hw0;

  // stage x tile: 2048 floats, 2 x float4 per thread, fully coalesced
  #pragma unroll
  for (int r = 0; r < 2; ++r) {
    int idx = r * 256 + tid;        // 0..511
    int c   = idx >> 3;
    int p4  = (idx & 7) * 4;
    *reinterpret_cast<float4*>(&xs[c*32 + p4]) =
        *reinterpret_cast<const float4*>(xb + (size_t)c * HWP + p4);
  }
  __syncthreads();

  const int o = tid & 63;
  const int g = __builtin_amdgcn_readfirstlane((int)(tid >> 6));   // pixel group 0..3
  const float* xg = &xs[g * 8];

  float accq[8], acck[8], accv[8];
  const float bq = b1[o], bk = b2[o], bv = b3[o];
  #pragma unroll
  for (int p = 0; p < 8; ++p) { accq[p] = bq; acck[p] = bk; accv[p] = bv; }

  float4 xbuf[2][4];
  float4 wqb[2], wkb[2], wvb[2];

  // prologue: channels 0,1 and weights for c4=0
  xbuf[0][0] = *reinterpret_cast<const float4*>(xg + 0*32);
  xbuf[0][1] = *reinterpret_cast<const float4*>(xg + 0*32 + 4);
  xbuf[0][2] = *reinterpret_cast<const float4*>(xg + 1*32);
  xbuf[0][3] = *reinterpret_cast<const float4*>(xg + 1*32 + 4);
  wqb[0] = *reinterpret_cast<const float4*>(w1P + o*4);
  wkb[0] = *reinterpret_cast<const float4*>(w2P + o*4);
  wvb[0] = *reinterpret_cast<const float4*>(w3P + o*4);

  #pragma unroll
  for (int ph = 0; ph < 32; ++ph) {          // phase = 2 channels
    const int cur  = ph & 1, nxt = cur ^ 1;
    const int c4   = ph >> 1;
    const int wsel = c4 & 1;
    // prefetch next 2 channels of x
    if (ph < 31) {
      const int cn = (ph + 1) * 2;
      xbuf[nxt][0] = *reinterpret_cast<const float4*>(xg + (cn+0)*32);
      xbuf[nxt][1] = *reinterpret_cast<const float4*>(xg + (cn+0)*32 + 4);
      xbuf[nxt][2] = *reinterpret_cast<const float4*>(xg + (cn+1)*32);
      xbuf[nxt][3] = *reinterpret_cast<const float4*>(xg + (cn+1)*32 + 4);
    }
    // prefetch next c4's weights during the first half of this c4
    if (cur == 0 && c4 < 15) {
      wqb[wsel^1] = *reinterpret_cast<const float4*>(w1P + (c4+1)*256 + o*4);
      wkb[wsel^1] = *reinterpret_cast<const float4*>(w2P + (c4+1)*256 + o*4);
      wvb[wsel^1] = *reinterpret_cast<const float4*>(w3P + (c4+1)*256 + o*4);
    }
    const float wq0 = fcomp(wqb[wsel], cur*2), wq1 = fcomp(wqb[wsel], cur*2+1);
    const float wk0 = fcomp(wkb[wsel], cur*2), wk1 = fcomp(wkb[wsel], cur*2+1);
    const float wv0 = fcomp(wvb[wsel], cur*2), wv1 = fcomp(wvb[wsel], cur*2+1);
    #pragma unroll
    for (int p = 0; p < 8; ++p) {
      const float x0 = (p < 4) ? fcomp(xbuf[cur][0], p) : fcomp(xbuf[cur][1], p-4);
      const float x1 = (p < 4) ? fcomp(xbuf[cur][2], p) : fcomp(xbuf[cur][3], p-4);
      accq[p] = fmaf(wq0, x0, accq[p]);
      acck[p] = fmaf(wk0, x0, acck[p]);
      accv[p] = fmaf(wv0, x0, accv[p]);
      accq[p] = fmaf(wq1, x1, accq[p]);
      acck[p] = fmaf(wk1, x1, acck[p]);
      accv[p] = fmaf(wv1, x1, accv[p]);
    }
  }

  const int pbase = pix0 + g * 8;
  #pragma unroll
  for (int p = 0; p < 8; ++p) {
    size_t off = (size_t)(pbase + p) * 64 + o;   // lanes o consecutive -> 256B stores
    q[off] = accq[p]; k[off] = acck[p]; v[off] = accv[p];
  }
}

// ---------------- fused attention + conv, single pass, online softmax, K-row dbuf ----------------
// block = 256 threads = 16 pixels; 16-lane group per pixel, lane holds 4 channels.
__global__ __launch_bounds__(256) void attn_kernel(
    const float* __restrict__ q, const float* __restrict__ k, const float* __restrict__ v,
    const float* __restrict__ wp, const float* __restrict__ tab,
    const float* __restrict__ b_dep, const float* __restrict__ rate1, const float* __restrict__ rate2,
    float* __restrict__ out)
{
  __shared__ float stab[27 * 64];
  __shared__ float sbd[64];
  __shared__ float sout[64 * 17];

  const int tid  = threadIdx.x;
  for (int i = tid; i < 27*64; i += 256) stab[i] = tab[i];
  if (tid < 64) sbd[tid] = b_dep[tid];
  __syncthreads();

  const int lane = tid & 63;
  const int wid  = __builtin_amdgcn_readfirstlane((int)(tid >> 6));
  const int grp  = lane >> 4;          // group within wave (0..3)
  const int sl   = lane & 15;          // sub-lane = d/4

  // XCD-chunked swizzle: 1568 blocks, 196 per image -> XCD n consumes image n
  int bid = (int)blockIdx.x;
  bid = (bid & 7) * 196 + (bid >> 3);

  const int pixbase = bid * 16;
  const int pl  = wid * 4 + grp;       // local pixel 0..15
  const int pix = pixbase + pl;
  const int n   = pix / HWP;           // uniform per block
  const int hw  = pix - n * HWP;
  const int h   = hw / WWID;
  const int w   = hw - h * WWID;

  const size_t nbase = (size_t)n * HWP * 64;
  const float4 q4 = *reinterpret_cast<const float4*>(q + nbase + (size_t)hw * 64 + sl * 4);

  // reflected coordinates for the 5x5 window
  int hr[5], wr[5];
  #pragma unroll
  for (int i = 0; i < 5; ++i) {
    int t = h + i - 2; hr[i] = t < 0 ? -t : (t >= HH ? 2*HH - 2 - t : t);
    t = w + i - 2;     wr[i] = t < 0 ? -t : (t >= WWID ? 2*WWID - 2 - t : t);
  }

  const float* kb = k + nbase + sl * 4;
  const float* vb = v + nbase + sl * 4;

  // prefetch row-0 K (latency hidden under the RPE reductions below)
  float4 ka[5];
  {
    const float* krow = kb + (size_t)(hr[0] * WWID) * 64;
    #pragma unroll
    for (int j = 0; j < 5; ++j) ka[j] = *reinterpret_cast<const float4*>(krow + wr[j] * 64);
  }

  // RPE dots; wp layout [d][2]
  const float4 wa = *reinterpret_cast<const float4*>(wp + 8 * sl);
  const float4 wb = *reinterpret_cast<const float4*>(wp + 8 * sl + 4);
  const float4 wpx4 = {wa.x, wa.z, wb.x, wb.z};
  const float4 wpy4 = {wa.y, wa.w, wb.y, wb.w};
  const float qw0 = grp_sum(dot4(q4, wpx4));
  const float qw1 = grp_sum(dot4(q4, wpy4));

  const float C = 2.0f / 55.0f;
  const float A0 = 0.125f * qw0 * C;   // coeff for (w - wr)
  const float A1 = 0.125f * qw1 * C;   // coeff for (h - hr)

  float m = -__builtin_inff();
  float s = 0.f;
  float4 oatt = {0.f, 0.f, 0.f, 0.f};
  float4 cacc = {0.f, 0.f, 0.f, 0.f};

  #pragma unroll
  for (int i = 0; i < 5; ++i) {
    // issue this row's V loads and next row's K loads before consuming ka
    const float* vrow = vb + (size_t)(hr[i] * WWID) * 64;
    float4 va[5];
    #pragma unroll
    for (int j = 0; j < 5; ++j) va[j] = *reinterpret_cast<const float4*>(vrow + wr[j] * 64);
    float4 kn[5];
    if (i < 4) {
      const float* krow = kb + (size_t)(hr[i+1] * WWID) * 64;
      #pragma unroll
      for (int j = 0; j < 5; ++j) kn[j] = *reinterpret_cast<const float4*>(krow + wr[j] * 64);
    }

    const float rh = A1 * (float)(h - hr[i]);
    float att[5];
    #pragma unroll
    for (int j = 0; j < 5; ++j) {
      const float d8 = grp_sum(dot4(q4, ka[j]));
      att[j] = 0.125f * d8 + A0 * (float)(w - wr[j]) + rh;
    }

    // online softmax update
    float mrow = att[0];
    #pragma unroll
    for (int j = 1; j < 5; ++j) mrow = fmaxf(mrow, att[j]);
    const float mnew = fmaxf(m, mrow);
    const float scale = __expf(m - mnew);
    m = mnew;
    s *= scale;
    oatt.x *= scale; oatt.y *= scale; oatt.z *= scale; oatt.w *= scale;
    #pragma unroll
    for (int j = 0; j < 5; ++j) {
      const float p = __expf(att[j] - m);
      s += p;
      oatt.x = fmaf(p, va[j].x, oatt.x);
      oatt.y = fmaf(p, va[j].y, oatt.y);
      oatt.z = fmaf(p, va[j].z, oatt.z);
      oatt.w = fmaf(p, va[j].w, oatt.w);
    }

    // conv branch: taps live in window rows 1..3, cols 1..3 (reuse ka/va regs)
    if (i >= 1 && i <= 3) {
      const int hh = h + i - 2;
      #pragma unroll
      for (int kw = 0; kw < 3; ++kw) {
        const int wc = w + kw - 1;
        const float mk = (((unsigned)hh < HH) && ((unsigned)wc < WWID)) ? 1.f : 0.f;
        const int tap = (i-1)*3 + kw;
        const int j = kw + 1;
        const float4 tq = *reinterpret_cast<const float4*>(&stab[(0*9 + tap)*64 + sl*4]);
        const float4 tk = *reinterpret_cast<const float4*>(&stab[(1*9 + tap)*64 + sl*4]);
        const float4 tv = *reinterpret_cast<const float4*>(&stab[(2*9 + tap)*64 + sl*4]);
        const float4 qn = *reinterpret_cast<const float4*>(q + nbase + (size_t)(hr[i]*WWID + wr[j]) * 64 + sl * 4);
        float sx = tq.x*qn.x; sx = fmaf(tk.x, ka[j].x, sx); sx = fmaf(tv.x, va[j].x, sx);
        float sy = tq.y*qn.y; sy = fmaf(tk.y, ka[j].y, sy); sy = fmaf(tv.y, va[j].y, sy);
        float sz = tq.z*qn.z; sz = fmaf(tk.z, ka[j].z, sz); sz = fmaf(tv.z, va[j].z, sz);
        float sw = tq.w*qn.w; sw = fmaf(tk.w, ka[j].w, sw); sw = fmaf(tv.w, va[j].w, sw);
        cacc.x = fmaf(mk, sx, cacc.x);
        cacc.y = fmaf(mk, sy, cacc.y);
        cacc.z = fmaf(mk, sz, cacc.z);
        cacc.w = fmaf(mk, sw, cacc.w);
      }
    }

    if (i < 4) {
      #pragma unroll
      for (int j = 0; j < 5; ++j) ka[j] = kn[j];   // full unroll -> pure renaming
    }
  }

  const float inv = 1.0f / s;
  const float bdx = sbd[sl*4+0], bdy = sbd[sl*4+1], bdz = sbd[sl*4+2], bdw = sbd[sl*4+3];
  const float r1 = rate1[0] * inv;
  const float r2 = rate2[0];

  float res[4];
  res[0] = r1 * oatt.x + r2 * (cacc.x + bdx);
  res[1] = r1 * oatt.y + r2 * (cacc.y + bdy);
  res[2] = r1 * oatt.z + r2 * (cacc.z + bdz);
  res[3] = r1 * oatt.w + r2 * (cacc.w + bdw);

  // stage to LDS [ch][16 px + pad] then write coalesced float4 per thread
  #pragma unroll
  for (int e = 0; e < 4; ++e)
    sout[(4*sl + e)*17 + pl] = res[e];
  __syncthreads();

  const int c  = tid >> 2;
  const int e4 = (tid & 3) * 4;
  const int hw0 = pixbase - n * HWP;
  float4 o4 = {sout[c*17 + e4 + 0], sout[c*17 + e4 + 1],
               sout[c*17 + e4 + 2], sout[c*17 + e4 + 3]};
  *reinterpret_cast<float4*>(out + ((size_t)(n*64 + c))*HWP + hw0 + e4) = o4;
}

extern "C" void kernel_launch(void* const* d_in, const int* in_sizes, int n_in,
                              void* d_out, int out_size, void* d_ws, size_t ws_size,
                              hipStream_t stream) {
  const float* x     = (const float*)d_in[0];
  const float* w1    = (const float*)d_in[1];
  const float* b1    = (const float*)d_in[2];
  const float* w2    = (const float*)d_in[3];
  const float* b2    = (const float*)d_in[4];
  const float* w3    = (const float*)d_in[5];
  const float* b3    = (const float*)d_in[6];
  const float* wp    = (const float*)d_in[7];
  // d_in[8] = bp : cancels in the RPE difference, unused
  const float* w_fc  = (const float*)d_in[9];
  const float* w_dep = (const float*)d_in[10];
  const float* b_dep = (const float*)d_in[11];
  const float* rate1 = (const float*)d_in[12];
  const float* rate2 = (const float*)d_in[13];
  float* out = (float*)d_out;

  float* ws = (float*)d_ws;
  float* q   = ws;                       // NPIX*64
  float* k   = ws + (size_t)NPIX*64;
  float* v   = ws + (size_t)2*NPIX*64;
  float* w1P = ws + (size_t)3*NPIX*64;   // 4096
  float* w2P = w1P + 4096;
  float* w3P = w2P + 4096;
  float* tab = w3P + 4096;               // 27*64

  prep_kernel<<<16, 256, 0, stream>>>(w1, w2, w3, w_fc, w_dep, w1P, w2P, w3P, tab);
  qkv_kernel<<<NPIX/32, 256, 0, stream>>>(x, b1, b2, b3, w1P, w2P, w3P, q, k, v);
  attn_kernel<<<NPIX/16, 256, 0, stream>>>(q, k, v, wp, tab, b_dep, rate1, rate2, out);
}